// Round 2
// baseline (309.133 us; speedup 1.0000x reference)
//
#include <hip/hip_runtime.h>

typedef unsigned short u16;
typedef __attribute__((ext_vector_type(8))) short bf16x8;
typedef __attribute__((ext_vector_type(4))) float f32x4;

__device__ inline u16 f2bf(float f){
  union { float f; unsigned u; } v; v.f = f;
  unsigned r = v.u + 0x7FFFu + ((v.u >> 16) & 1u);
  return (u16)(r >> 16);
}
__device__ inline float bf2f(u16 u){
  union { unsigned u; float f; } v; v.u = ((unsigned)u) << 16;
  return v.f;
}

// ---------------- prep: split z (fp32 -> bf16 hi/lo) ----------------
__global__ __launch_bounds__(256) void split_f32(const float* __restrict__ x,
                                                 u16* __restrict__ hi,
                                                 u16* __restrict__ lo, int n4){
  int i = blockIdx.x * 256 + threadIdx.x;
  if (i >= n4) return;
  float4 v = ((const float4*)x)[i];
  float a0 = v.x, a1 = v.y, a2 = v.z, a3 = v.w;
  u16 h0 = f2bf(a0), h1 = f2bf(a1), h2 = f2bf(a2), h3 = f2bf(a3);
  ushort4 h; h.x = h0; h.y = h1; h.z = h2; h.w = h3;
  ushort4 l; l.x = f2bf(a0 - bf2f(h0)); l.y = f2bf(a1 - bf2f(h1));
  l.z = f2bf(a2 - bf2f(h2)); l.w = f2bf(a3 - bf2f(h3));
  ((ushort4*)hi)[i] = h;
  ((ushort4*)lo)[i] = l;
}

// ---------------- prep: transpose + split W (1024x1024, [d][n] -> [n][d]) ----------------
__global__ __launch_bounds__(256) void transpose_split_w(
    const float* __restrict__ Wq, const float* __restrict__ Wk, const float* __restrict__ Wv,
    u16* __restrict__ qh, u16* __restrict__ ql,
    u16* __restrict__ kh, u16* __restrict__ kl,
    u16* __restrict__ vh, u16* __restrict__ vl){
  const float* W; u16 *H, *L;
  if (blockIdx.z == 0){ W = Wq; H = qh; L = ql; }
  else if (blockIdx.z == 1){ W = Wk; H = kh; L = kl; }
  else { W = Wv; H = vh; L = vl; }
  __shared__ float t[64][65];
  int d0 = blockIdx.y * 64, n0 = blockIdx.x * 64;
  int tid = threadIdx.x;
  int r = tid >> 4, c4 = (tid & 15) * 4;
  for (int rr = r; rr < 64; rr += 16){
    float4 v = *(const float4*)&W[(size_t)(d0 + rr) * 1024 + n0 + c4];
    t[rr][c4 + 0] = v.x; t[rr][c4 + 1] = v.y; t[rr][c4 + 2] = v.z; t[rr][c4 + 3] = v.w;
  }
  __syncthreads();
  int n = tid >> 4, d4 = (tid & 15) * 4;
  for (int nn = n; nn < 64; nn += 16){
    float x0 = t[d4 + 0][nn], x1 = t[d4 + 1][nn], x2 = t[d4 + 2][nn], x3 = t[d4 + 3][nn];
    u16 h0 = f2bf(x0), h1 = f2bf(x1), h2 = f2bf(x2), h3 = f2bf(x3);
    ushort4 h; h.x = h0; h.y = h1; h.z = h2; h.w = h3;
    ushort4 l; l.x = f2bf(x0 - bf2f(h0)); l.y = f2bf(x1 - bf2f(h1));
    l.z = f2bf(x2 - bf2f(h2)); l.w = f2bf(x3 - bf2f(h3));
    *(ushort4*)&H[(size_t)(n0 + nn) * 1024 + d0 + d4] = h;
    *(ushort4*)&L[(size_t)(n0 + nn) * 1024 + d0 + d4] = l;
  }
}

// ---------------- GEMM: C[M,N] = A[M,K] * B[N,K]^T, bf16 MFMA ----------------
// SPLIT: both operands have hi/lo planes -> 3-MFMA chain (fp32-ish precision).
// EPI: 0 = fp32 C0;  1 = bf16 C0;  2 = split pair (bf16 hi->C0, lo->C1).
// Staging: 128x32 tile/plane; 256 threads x 32B (two uint4) per plane.
template<bool SPLIT, int EPI>
__global__ __launch_bounds__(256) void gemm_bt(
    const u16* __restrict__ Ah, const u16* __restrict__ Al, int lda,
    const u16* __restrict__ Bh, const u16* __restrict__ Bl, int ldb,
    void* __restrict__ C0, void* __restrict__ C1, int ldc, int K){
  constexpr int PL = SPLIT ? 2 : 1;
  __shared__ __align__(16) u16 sA[PL * 128 * 40];
  __shared__ __align__(16) u16 sB[PL * 128 * 40];
  u16* sAh = sA;           u16* sAl = sA + 128 * 40 * (PL - 1);
  u16* sBh = sB;           u16* sBl = sB + 128 * 40 * (PL - 1);

  const int tid = threadIdx.x;
  const int lane = tid & 63, wave = tid >> 6;
  const int wr = wave >> 1, wc = wave & 1;
  const int lr = lane & 15, kg = lane >> 4;

  const int m0 = blockIdx.y * 128, n0 = blockIdx.x * 128;
  const int srow = tid >> 1, shalf = tid & 1;
  const int sidx = srow * 40 + shalf * 16;

  const u16* ga_h = Ah + (size_t)(m0 + srow) * lda + shalf * 16;
  const u16* gb_h = Bh + (size_t)(n0 + srow) * ldb + shalf * 16;
  const u16* ga_l = SPLIT ? (Al + (size_t)(m0 + srow) * lda + shalf * 16) : nullptr;
  const u16* gb_l = SPLIT ? (Bl + (size_t)(n0 + srow) * ldb + shalf * 16) : nullptr;

  uint4 rah0, rah1, rbh0, rbh1;
  uint4 ral0 = {}, ral1 = {}, rbl0 = {}, rbl1 = {};
  rah0 = *(const uint4*)ga_h;       rah1 = *(const uint4*)(ga_h + 8);
  rbh0 = *(const uint4*)gb_h;       rbh1 = *(const uint4*)(gb_h + 8);
  if (SPLIT){
    ral0 = *(const uint4*)ga_l;     ral1 = *(const uint4*)(ga_l + 8);
    rbl0 = *(const uint4*)gb_l;     rbl1 = *(const uint4*)(gb_l + 8);
  }

  f32x4 acc[4][4];
  #pragma unroll
  for (int m = 0; m < 4; m++)
    #pragma unroll
    for (int n = 0; n < 4; n++)
      acc[m][n] = (f32x4){0.f, 0.f, 0.f, 0.f};

  const int KT = K >> 5;
  for (int kt = 0; kt < KT; ++kt){
    __syncthreads();
    *(uint4*)&sAh[sidx] = rah0;     *(uint4*)&sAh[sidx + 8] = rah1;
    *(uint4*)&sBh[sidx] = rbh0;     *(uint4*)&sBh[sidx + 8] = rbh1;
    if (SPLIT){
      *(uint4*)&sAl[sidx] = ral0;   *(uint4*)&sAl[sidx + 8] = ral1;
      *(uint4*)&sBl[sidx] = rbl0;   *(uint4*)&sBl[sidx + 8] = rbl1;
    }
    __syncthreads();
    if (kt + 1 < KT){
      ga_h += 32; gb_h += 32;
      rah0 = *(const uint4*)ga_h;   rah1 = *(const uint4*)(ga_h + 8);
      rbh0 = *(const uint4*)gb_h;   rbh1 = *(const uint4*)(gb_h + 8);
      if (SPLIT){
        ga_l += 32; gb_l += 32;
        ral0 = *(const uint4*)ga_l; ral1 = *(const uint4*)(ga_l + 8);
        rbl0 = *(const uint4*)gb_l; rbl1 = *(const uint4*)(gb_l + 8);
      }
    }
    bf16x8 afh[4], bfh[4], afl[4], bfl[4];
    #pragma unroll
    for (int m = 0; m < 4; m++){
      int rowa = wr * 64 + m * 16 + lr;
      afh[m] = *(const bf16x8*)&sAh[rowa * 40 + kg * 8];
      if (SPLIT) afl[m] = *(const bf16x8*)&sAl[rowa * 40 + kg * 8];
    }
    #pragma unroll
    for (int n = 0; n < 4; n++){
      int rowb = wc * 64 + n * 16 + lr;
      bfh[n] = *(const bf16x8*)&sBh[rowb * 40 + kg * 8];
      if (SPLIT) bfl[n] = *(const bf16x8*)&sBl[rowb * 40 + kg * 8];
    }
    #pragma unroll
    for (int m = 0; m < 4; m++)
      #pragma unroll
      for (int n = 0; n < 4; n++){
        acc[m][n] = __builtin_amdgcn_mfma_f32_16x16x32_bf16(afh[m], bfh[n], acc[m][n], 0, 0, 0);
        if (SPLIT){
          acc[m][n] = __builtin_amdgcn_mfma_f32_16x16x32_bf16(afl[m], bfh[n], acc[m][n], 0, 0, 0);
          acc[m][n] = __builtin_amdgcn_mfma_f32_16x16x32_bf16(afh[m], bfl[n], acc[m][n], 0, 0, 0);
        }
      }
  }

  const int row0 = m0 + wr * 64, col0 = n0 + wc * 64 + lr;
  #pragma unroll
  for (int m = 0; m < 4; m++)
    #pragma unroll
    for (int n = 0; n < 4; n++)
      #pragma unroll
      for (int r = 0; r < 4; r++){
        int row = row0 + m * 16 + kg * 4 + r;
        int col = col0 + n * 16;
        float x = acc[m][n][r];
        if (EPI == 0){
          ((float*)C0)[(size_t)row * ldc + col] = x;
        } else if (EPI == 1){
          ((u16*)C0)[(size_t)row * ldc + col] = f2bf(x);
        } else {
          u16 h = f2bf(x);
          ((u16*)C0)[(size_t)row * ldc + col] = h;
          ((u16*)C1)[(size_t)row * ldc + col] = f2bf(x - bf2f(h));
        }
      }
}

// ---------------- softmax over rows of S (4096 fp32), write P bf16 in-place ----------------
// P row i lives in the first 8KB of S row i's 16KB -> P has row stride 8192 u16 elements.
__global__ __launch_bounds__(256) void softmax_rows(float* __restrict__ S){
  int rrow = blockIdx.x;
  float* srow = S + (size_t)rrow * 4096;
  __shared__ float e[4096];
  __shared__ float red[4];
  int tid = threadIdx.x;

  float m = -1e30f;
  for (int i = tid * 4; i < 4096; i += 1024){
    float4 v = *(const float4*)(srow + i);
    m = fmaxf(m, fmaxf(fmaxf(v.x, v.y), fmaxf(v.z, v.w)));
  }
  for (int o = 32; o > 0; o >>= 1) m = fmaxf(m, __shfl_xor(m, o));
  if ((tid & 63) == 0) red[tid >> 6] = m;
  __syncthreads();
  m = fmaxf(fmaxf(red[0], red[1]), fmaxf(red[2], red[3]));

  float s = 0.f;
  for (int i = tid * 4; i < 4096; i += 1024){
    float4 v = *(const float4*)(srow + i);
    float4 ev;
    ev.x = __expf(v.x - m); ev.y = __expf(v.y - m);
    ev.z = __expf(v.z - m); ev.w = __expf(v.w - m);
    s += (ev.x + ev.y) + (ev.z + ev.w);
    *(float4*)&e[i] = ev;
  }
  for (int o = 32; o > 0; o >>= 1) s += __shfl_xor(s, o);
  __syncthreads();               // all reads of srow and red are done
  if ((tid & 63) == 0) red[tid >> 6] = s;
  __syncthreads();
  s = (red[0] + red[1]) + (red[2] + red[3]);

  float scale = 0.03125f / s;    // fold the post-softmax 1/sqrt(dk)=1/32 into P
  u16* prow = (u16*)((char*)S + (size_t)rrow * 16384);
  for (int i = tid * 4; i < 4096; i += 1024){
    float4 v = *(const float4*)&e[i];
    ushort4 o; o.x = f2bf(v.x * scale); o.y = f2bf(v.y * scale);
    o.z = f2bf(v.z * scale); o.w = f2bf(v.w * scale);
    *(ushort4*)(prow + i) = o;
  }
}

extern "C" void kernel_launch(void* const* d_in, const int* in_sizes, int n_in,
                              void* d_out, int out_size, void* d_ws, size_t ws_size,
                              hipStream_t stream){
  const float* z  = (const float*)d_in[0];
  const float* Wq = (const float*)d_in[1];
  const float* Wk = (const float*)d_in[2];
  const float* Wv = (const float*)d_in[3];
  char* ws = (char*)d_ws;
  const size_t MB = 1ull << 20;

  // persistent region (needed through PV): 40MB
  u16* q_hi = (u16*)(ws + 0 * MB);
  u16* q_lo = (u16*)(ws + 8 * MB);
  u16* k_hi = (u16*)(ws + 16 * MB);
  u16* k_lo = (u16*)(ws + 24 * MB);
  u16* v_t  = (u16*)(ws + 32 * MB);   // v^T [1024][4096] bf16
  // S region 40..104MB (64MB). Prep scratch overlaps it (dead before S is written).
  float* S   = (float*)(ws + 40 * MB);
  u16* z_hi  = (u16*)(ws + 40 * MB);
  u16* z_lo  = (u16*)(ws + 48 * MB);
  u16* wqt_h = (u16*)(ws + 56 * MB);
  u16* wqt_l = (u16*)(ws + 58 * MB);
  u16* wkt_h = (u16*)(ws + 60 * MB);
  u16* wkt_l = (u16*)(ws + 62 * MB);
  u16* wvt_h = (u16*)(ws + 64 * MB);
  u16* wvt_l = (u16*)(ws + 66 * MB);

  // prep
  split_f32<<<4096, 256, 0, stream>>>(z, z_hi, z_lo, 4096 * 1024 / 4);
  transpose_split_w<<<dim3(16, 16, 3), 256, 0, stream>>>(Wq, Wk, Wv,
      wqt_h, wqt_l, wkt_h, wkt_l, wvt_h, wvt_l);

  // q = z @ Wq  (split x split, epilogue writes hi/lo pair)   M=4096 N=1024 K=1024
  gemm_bt<true, 2><<<dim3(8, 32), 256, 0, stream>>>(z_hi, z_lo, 1024,
      wqt_h, wqt_l, 1024, q_hi, q_lo, 1024, 1024);
  // k = z @ Wk
  gemm_bt<true, 2><<<dim3(8, 32), 256, 0, stream>>>(z_hi, z_lo, 1024,
      wkt_h, wkt_l, 1024, k_hi, k_lo, 1024, 1024);
  // v^T[n][s] = sum_d Wvt[n][d] * z[s][d]   M=1024 N=4096 K=1024 (plain bf16)
  gemm_bt<false, 1><<<dim3(32, 8), 256, 0, stream>>>(wvt_h, nullptr, 1024,
      z_hi, nullptr, 1024, v_t, nullptr, 4096, 1024);

  // S = q @ k^T  fp32  M=N=4096 K=1024 (split x split)
  gemm_bt<true, 0><<<dim3(32, 32), 256, 0, stream>>>(q_hi, q_lo, 1024,
      k_hi, k_lo, 1024, S, nullptr, 4096, 1024);

  // softmax rows, P bf16 in-place (row stride 8192 u16), scale 1/32 folded in
  softmax_rows<<<4096, 256, 0, stream>>>(S);

  // out = P @ v  (A = P [4096, 4096] lda=8192, B = v^T [1024][4096])  fp32 out
  gemm_bt<false, 0><<<dim3(8, 32), 256, 0, stream>>>((u16*)S, nullptr, 8192,
      v_t, nullptr, 4096, (float*)d_out, nullptr, 1024, 4096);
}